// Round 9
// baseline (3698.379 us; speedup 1.0000x reference)
//
#include <hip/hip_runtime.h>
#include <math.h>

// Problem constants: B=8192, N=4096, D=2048, M=1024, C=64, K=100
#define LN_EPS 1e-6

typedef __attribute__((ext_vector_type(8))) short short8v;   // 8 bf16 (4 VGPR) MFMA A/B frag
typedef __attribute__((ext_vector_type(4))) float f32x4;     // MFMA C/D frag
typedef unsigned short u16;

// ---------------------------------------------------------------------------
// split3: x == h + m + l (3 bf16 limbs), residuals exact (Sterbenz), RN.
// ---------------------------------------------------------------------------
__device__ __forceinline__ u16 bf16rn(float x) {
  unsigned int u = __float_as_uint(x);
  return (u16)((u + 0x7FFFu + ((u >> 16) & 1u)) >> 16);
}
__device__ __forceinline__ float bf16tof(u16 h) {
  return __uint_as_float(((unsigned int)h) << 16);
}
__device__ __forceinline__ void split3f(float x, u16& h, u16& m, u16& l) {
  h = bf16rn(x);
  float r1 = x - bf16tof(h);
  m = bf16rn(r1);
  float r2 = r1 - bf16tof(m);
  l = bf16rn(r2);
}

// ---------------------------------------------------------------------------
// f32 tiled GEMM (round-4/7 proven codegen: 72 VGPR, no scratch).
// C[Mx,Nx] = A[Mx,Kx] @ B ; TRANSB: B given as [Nx,Kx].
// ---------------------------------------------------------------------------
template <int TRANSB>
__global__ __launch_bounds__(256) void gemm128(const float* __restrict__ A,
                                               const float* __restrict__ B,
                                               float* __restrict__ C,
                                               int Mx, int Nx, int Kx) {
  __shared__ float As[16][132];
  __shared__ float Bs[16][132];
  const int tid = threadIdx.x;
  const int bm = blockIdx.y * 128;
  const int bn = blockIdx.x * 128;
  const int ty = tid >> 4;
  const int tx = tid & 15;

  float acc[2][2][4][4] = {};

  for (int k0 = 0; k0 < Kx; k0 += 16) {
#pragma unroll
    for (int it = 0; it < 2; ++it) {
      const int idx = tid + it * 256;
      const int r = idx >> 2;
      const int c4 = (idx & 3) << 2;
      float4 av = *reinterpret_cast<const float4*>(A + (size_t)(bm + r) * Kx + k0 + c4);
      As[c4 + 0][r] = av.x;
      As[c4 + 1][r] = av.y;
      As[c4 + 2][r] = av.z;
      As[c4 + 3][r] = av.w;
    }
    if (TRANSB) {
#pragma unroll
      for (int it = 0; it < 2; ++it) {
        const int idx = tid + it * 256;
        const int r = idx >> 2;
        const int c4 = (idx & 3) << 2;
        float4 bv = *reinterpret_cast<const float4*>(B + (size_t)(bn + r) * Kx + k0 + c4);
        Bs[c4 + 0][r] = bv.x;
        Bs[c4 + 1][r] = bv.y;
        Bs[c4 + 2][r] = bv.z;
        Bs[c4 + 3][r] = bv.w;
      }
    } else {
#pragma unroll
      for (int it = 0; it < 2; ++it) {
        const int idx = tid + it * 256;
        const int kr = idx >> 5;
        const int c4 = (idx & 31) << 2;
        float4 bv = *reinterpret_cast<const float4*>(B + (size_t)(k0 + kr) * Nx + bn + c4);
        *reinterpret_cast<float4*>(&Bs[kr][c4]) = bv;
      }
    }
    __syncthreads();

#pragma unroll
    for (int kk = 0; kk < 16; ++kk) {
      float a0[4], a1[4], b0[4], b1[4];
      *reinterpret_cast<float4*>(a0) = *reinterpret_cast<const float4*>(&As[kk][ty * 4]);
      *reinterpret_cast<float4*>(a1) = *reinterpret_cast<const float4*>(&As[kk][ty * 4 + 64]);
      *reinterpret_cast<float4*>(b0) = *reinterpret_cast<const float4*>(&Bs[kk][tx * 4]);
      *reinterpret_cast<float4*>(b1) = *reinterpret_cast<const float4*>(&Bs[kk][tx * 4 + 64]);
#pragma unroll
      for (int i = 0; i < 4; ++i)
#pragma unroll
        for (int j = 0; j < 4; ++j) {
          acc[0][0][i][j] = fmaf(a0[i], b0[j], acc[0][0][i][j]);
          acc[0][1][i][j] = fmaf(a0[i], b1[j], acc[0][1][i][j]);
          acc[1][0][i][j] = fmaf(a1[i], b0[j], acc[1][0][i][j]);
          acc[1][1][i][j] = fmaf(a1[i], b1[j], acc[1][1][i][j]);
        }
    }
    __syncthreads();
  }

#pragma unroll
  for (int ri = 0; ri < 2; ++ri)
#pragma unroll
    for (int i = 0; i < 4; ++i) {
      const size_t row = (size_t)(bm + ri * 64 + ty * 4 + i);
#pragma unroll
      for (int ci = 0; ci < 2; ++ci) {
        float4 o = make_float4(acc[ri][ci][i][0], acc[ri][ci][i][1], acc[ri][ci][i][2],
                               acc[ri][ci][i][3]);
        *reinterpret_cast<float4*>(C + row * Nx + bn + ci * 64 + tx * 4) = o;
      }
    }
}

// Fused k & v projections (blockIdx.z selects weight/output).
__global__ __launch_bounds__(256) void gemm128_kv(const float* __restrict__ A,
                                                  const float* __restrict__ W_k,
                                                  const float* __restrict__ W_v,
                                                  float* __restrict__ kOut,
                                                  float* __restrict__ vOut,
                                                  int Mx, int Nx, int Kx) {
  const float* __restrict__ B = (blockIdx.z == 0) ? W_k : W_v;
  float* __restrict__ C = (blockIdx.z == 0) ? kOut : vOut;

  __shared__ float As[16][132];
  __shared__ float Bs[16][132];
  const int tid = threadIdx.x;
  const int bm = blockIdx.y * 128;
  const int bn = blockIdx.x * 128;
  const int ty = tid >> 4;
  const int tx = tid & 15;

  float acc[2][2][4][4] = {};

  for (int k0 = 0; k0 < Kx; k0 += 16) {
#pragma unroll
    for (int it = 0; it < 2; ++it) {
      const int idx = tid + it * 256;
      const int r = idx >> 2;
      const int c4 = (idx & 3) << 2;
      float4 av = *reinterpret_cast<const float4*>(A + (size_t)(bm + r) * Kx + k0 + c4);
      As[c4 + 0][r] = av.x;
      As[c4 + 1][r] = av.y;
      As[c4 + 2][r] = av.z;
      As[c4 + 3][r] = av.w;
    }
#pragma unroll
    for (int it = 0; it < 2; ++it) {
      const int idx = tid + it * 256;
      const int kr = idx >> 5;
      const int c4 = (idx & 31) << 2;
      float4 bv = *reinterpret_cast<const float4*>(B + (size_t)(k0 + kr) * Nx + bn + c4);
      *reinterpret_cast<float4*>(&Bs[kr][c4]) = bv;
    }
    __syncthreads();

#pragma unroll
    for (int kk = 0; kk < 16; ++kk) {
      float a0[4], a1[4], b0[4], b1[4];
      *reinterpret_cast<float4*>(a0) = *reinterpret_cast<const float4*>(&As[kk][ty * 4]);
      *reinterpret_cast<float4*>(a1) = *reinterpret_cast<const float4*>(&As[kk][ty * 4 + 64]);
      *reinterpret_cast<float4*>(b0) = *reinterpret_cast<const float4*>(&Bs[kk][tx * 4]);
      *reinterpret_cast<float4*>(b1) = *reinterpret_cast<const float4*>(&Bs[kk][tx * 4 + 64]);
#pragma unroll
      for (int i = 0; i < 4; ++i)
#pragma unroll
        for (int j = 0; j < 4; ++j) {
          acc[0][0][i][j] = fmaf(a0[i], b0[j], acc[0][0][i][j]);
          acc[0][1][i][j] = fmaf(a0[i], b1[j], acc[0][1][i][j]);
          acc[1][0][i][j] = fmaf(a1[i], b0[j], acc[1][0][i][j]);
          acc[1][1][i][j] = fmaf(a1[i], b1[j], acc[1][1][i][j]);
        }
    }
    __syncthreads();
  }

#pragma unroll
  for (int ri = 0; ri < 2; ++ri)
#pragma unroll
    for (int i = 0; i < 4; ++i) {
      const size_t row = (size_t)(bm + ri * 64 + ty * 4 + i);
#pragma unroll
      for (int ci = 0; ci < 2; ++ci) {
        float4 o = make_float4(acc[ri][ci][i][0], acc[ri][ci][i][1], acc[ri][ci][i][2],
                               acc[ri][ci][i][3]);
        *reinterpret_cast<float4*>(C + row * Nx + bn + ci * 64 + tx * 4) = o;
      }
    }
}

// ---------------------------------------------------------------------------
// split3 MFMA GEMM: C[Mx,Nx] f32 = A @ B^T where A-splits are [Mx][Kx] bf16
// limbs and B-splits are [Nx][Kx] bf16 limbs (both K-contiguous).
// 128x128 tile, 4 waves (2x2), per-wave 64x64 via 4x4 frags of 16x16x32 MFMA.
// 6 MFMAs per fragment pair: hh, hm, mh, mm, hl, lh (f32-grade accuracy).
// LDS rows padded to 40 ushorts (80B) -> 2-way bank aliasing (free).
// ---------------------------------------------------------------------------
__global__ __launch_bounds__(256, 2) void mfma_bt(
    const u16* __restrict__ Ah, const u16* __restrict__ Am, const u16* __restrict__ Al,
    const u16* __restrict__ Bh, const u16* __restrict__ Bm, const u16* __restrict__ Bl,
    float* __restrict__ C, int Mx, int Nx, int Kx) {
  __shared__ u16 lds[6 * 128 * 40];  // 60 KB
  const int tid = threadIdx.x;
  const int lane = tid & 63;
  const int wid = tid >> 6;
  const int wr = wid >> 1, wc = wid & 1;
  const int bm = blockIdx.y * 128, bn = blockIdx.x * 128;

  f32x4 acc[4][4] = {};

  for (int k0 = 0; k0 < Kx; k0 += 32) {
    // ---- stage 6 tiles (A h/m/l rows bm.., B h/m/l rows bn..), [row][32k]+pad
    const u16* srcs[6] = {Ah, Am, Al, Bh, Bm, Bl};
#pragma unroll
    for (int t = 0; t < 6; ++t) {
      const u16* sp = srcs[t];
      const int rbase = (t < 3) ? bm : bn;
#pragma unroll
      for (int it = 0; it < 2; ++it) {
        const int gidx = tid + it * 256;     // 0..511
        const int row = gidx >> 2;           // 0..127
        const int slot = gidx & 3;           // 4 x 8 ushorts = 32 k
        uint4 d = *reinterpret_cast<const uint4*>(sp + (size_t)(rbase + row) * Kx + k0 +
                                                  slot * 8);
        *reinterpret_cast<uint4*>(&lds[t * 5120 + row * 40 + slot * 8]) = d;
      }
    }
    __syncthreads();

    // ---- fragment reads: lane l -> row (l&15), k-chunk (l>>4)*8
    short8v a[4][3], b[4][3];
#pragma unroll
    for (int r = 0; r < 4; ++r)
#pragma unroll
      for (int t = 0; t < 3; ++t)
        a[r][t] = *reinterpret_cast<const short8v*>(
            &lds[t * 5120 + (wr * 64 + r * 16 + (lane & 15)) * 40 + (lane >> 4) * 8]);
#pragma unroll
    for (int c = 0; c < 4; ++c)
#pragma unroll
      for (int t = 0; t < 3; ++t)
        b[c][t] = *reinterpret_cast<const short8v*>(
            &lds[(3 + t) * 5120 + (wc * 64 + c * 16 + (lane & 15)) * 40 + (lane >> 4) * 8]);

#pragma unroll
    for (int r = 0; r < 4; ++r)
#pragma unroll
      for (int c = 0; c < 4; ++c) {
        f32x4 t0 = acc[r][c];
        t0 = __builtin_amdgcn_mfma_f32_16x16x32_bf16(a[r][0], b[c][0], t0, 0, 0, 0);
        t0 = __builtin_amdgcn_mfma_f32_16x16x32_bf16(a[r][0], b[c][1], t0, 0, 0, 0);
        t0 = __builtin_amdgcn_mfma_f32_16x16x32_bf16(a[r][1], b[c][0], t0, 0, 0, 0);
        t0 = __builtin_amdgcn_mfma_f32_16x16x32_bf16(a[r][1], b[c][1], t0, 0, 0, 0);
        t0 = __builtin_amdgcn_mfma_f32_16x16x32_bf16(a[r][0], b[c][2], t0, 0, 0, 0);
        t0 = __builtin_amdgcn_mfma_f32_16x16x32_bf16(a[r][2], b[c][0], t0, 0, 0, 0);
        acc[r][c] = t0;
      }
    __syncthreads();
  }

  // ---- epilogue: C/D layout col = lane&15, row = (lane>>4)*4 + j  [m89/m91]
#pragma unroll
  for (int r = 0; r < 4; ++r)
#pragma unroll
    for (int c = 0; c < 4; ++c)
#pragma unroll
      for (int j = 0; j < 4; ++j) {
        const int row = bm + wr * 64 + r * 16 + (lane >> 4) * 4 + j;
        const int col = bn + wc * 64 + c * 16 + (lane & 15);
        C[(size_t)row * Nx + col] = acc[r][c][j];
      }
}

// ---------------------------------------------------------------------------
// Elementwise split3 of an f32 array into 3 bf16-limb arrays.
// ---------------------------------------------------------------------------
__global__ __launch_bounds__(256) void split3k(const float* __restrict__ in,
                                               u16* __restrict__ h, u16* __restrict__ m,
                                               u16* __restrict__ l, int n4) {
  for (size_t i = (size_t)blockIdx.x * 256 + threadIdx.x; i < (size_t)n4;
       i += (size_t)gridDim.x * 256) {
    float4 v = reinterpret_cast<const float4*>(in)[i];
    u16 hh[4], mm[4], ll[4];
    split3f(v.x, hh[0], mm[0], ll[0]);
    split3f(v.y, hh[1], mm[1], ll[1]);
    split3f(v.z, hh[2], mm[2], ll[2]);
    split3f(v.w, hh[3], mm[3], ll[3]);
    reinterpret_cast<uint2*>(h)[i] = *reinterpret_cast<const uint2*>(hh);
    reinterpret_cast<uint2*>(m)[i] = *reinterpret_cast<const uint2*>(mm);
    reinterpret_cast<uint2*>(l)[i] = *reinterpret_cast<const uint2*>(ll);
  }
}

// ---------------------------------------------------------------------------
// Transpose + split3: in [R][Cc] f32 -> out limbs [Cc][R] bf16.
// ---------------------------------------------------------------------------
__global__ __launch_bounds__(256) void tsplit3(const float* __restrict__ in,
                                               u16* __restrict__ th, u16* __restrict__ tm,
                                               u16* __restrict__ tl, int R, int Cc) {
  __shared__ float t[32][33];
  const int tid = threadIdx.x;
  const int tx = tid & 31, ty = tid >> 5;  // 32 x 8
  const int r0 = blockIdx.y * 32, c0 = blockIdx.x * 32;
#pragma unroll
  for (int j = 0; j < 4; ++j)
    t[ty + 8 * j][tx] = in[(size_t)(r0 + ty + 8 * j) * Cc + c0 + tx];
  __syncthreads();
#pragma unroll
  for (int j = 0; j < 4; ++j) {
    const int cl = ty + 8 * j;
    float x = t[tx][cl];
    u16 h, m, l;
    split3f(x, h, m, l);
    const size_t o = (size_t)(c0 + cl) * R + r0 + tx;
    th[o] = h;
    tm[o] = m;
    tl[o] = l;
  }
}

// ---------------------------------------------------------------------------
// Row softmax over N=4096 (scale 1/32 folded in) -> writes bf16-limb splits
// of the probabilities directly (PV consumes splits; no f32 write-back).
// ---------------------------------------------------------------------------
__global__ __launch_bounds__(256) void softmax_split(const float* __restrict__ S,
                                                     u16* __restrict__ Ph,
                                                     u16* __restrict__ Pm,
                                                     u16* __restrict__ Pl) {
  const size_t row = blockIdx.x;
  const float* p = S + row * 4096;
  const int tid = threadIdx.x;
  const int wid = tid >> 6, lane = tid & 63;
  __shared__ float red[4];

  float x[16];
#pragma unroll
  for (int i = 0; i < 4; ++i) {
    float4 v = *reinterpret_cast<const float4*>(p + i * 1024 + tid * 4);
    x[i * 4 + 0] = v.x;
    x[i * 4 + 1] = v.y;
    x[i * 4 + 2] = v.z;
    x[i * 4 + 3] = v.w;
  }
  float m = x[0];
#pragma unroll
  for (int i = 1; i < 16; ++i) m = fmaxf(m, x[i]);
  for (int off = 32; off; off >>= 1) m = fmaxf(m, __shfl_xor(m, off));
  if (lane == 0) red[wid] = m;
  __syncthreads();
  if (tid == 0) red[0] = fmaxf(fmaxf(red[0], red[1]), fmaxf(red[2], red[3]));
  __syncthreads();
  m = red[0];

  const float sc = 0.03125f;  // 1/sqrt(1024)
  float e[16];
  float s = 0.f;
#pragma unroll
  for (int i = 0; i < 16; ++i) {
    e[i] = expf((x[i] - m) * sc);
    s += e[i];
  }
  for (int off = 32; off; off >>= 1) s += __shfl_xor(s, off);
  if (lane == 0) red[wid] = s;
  __syncthreads();
  if (tid == 0) red[0] = red[0] + red[1] + red[2] + red[3];
  __syncthreads();
  const float inv = 1.f / red[0];

#pragma unroll
  for (int i = 0; i < 4; ++i) {
    u16 hh[4], mm[4], ll[4];
#pragma unroll
    for (int j = 0; j < 4; ++j) split3f(e[i * 4 + j] * inv, hh[j], mm[j], ll[j]);
    const size_t o = row * 4096 + i * 1024 + tid * 4;
    *reinterpret_cast<uint2*>(Ph + o) = *reinterpret_cast<const uint2*>(hh);
    *reinterpret_cast<uint2*>(Pm + o) = *reinterpret_cast<const uint2*>(mm);
    *reinterpret_cast<uint2*>(Pl + o) = *reinterpret_cast<const uint2*>(ll);
  }
}

// ---------------------------------------------------------------------------
// attended = attRaw*0.1 + q, then LayerNorm over M=1024 (f64 statistics).
// ---------------------------------------------------------------------------
__global__ __launch_bounds__(256) void ln_resid(const float* __restrict__ attRaw,
                                                const float* __restrict__ q,
                                                const float* __restrict__ gamma,
                                                const float* __restrict__ beta,
                                                float* __restrict__ out) {
  const size_t row = blockIdx.x;
  const int tid = threadIdx.x;
  const int wid = tid >> 6, lane = tid & 63;
  __shared__ double redd[4];

  float4 a = *reinterpret_cast<const float4*>(attRaw + row * 1024 + tid * 4);
  float4 qq = *reinterpret_cast<const float4*>(q + row * 1024 + tid * 4);
  float x[4];
  x[0] = fmaf(0.1f, a.x, qq.x);
  x[1] = fmaf(0.1f, a.y, qq.y);
  x[2] = fmaf(0.1f, a.z, qq.z);
  x[3] = fmaf(0.1f, a.w, qq.w);

  double s = (double)x[0] + (double)x[1] + (double)x[2] + (double)x[3];
  for (int off = 32; off; off >>= 1) s += __shfl_xor(s, off);
  if (lane == 0) redd[wid] = s;
  __syncthreads();
  if (tid == 0) redd[0] = redd[0] + redd[1] + redd[2] + redd[3];
  __syncthreads();
  const double mu = redd[0] * (1.0 / 1024.0);
  __syncthreads();

  double d2 = 0.0;
#pragma unroll
  for (int i = 0; i < 4; ++i) {
    double d = (double)x[i] - mu;
    d2 += d * d;
  }
  for (int off = 32; off; off >>= 1) d2 += __shfl_xor(d2, off);
  if (lane == 0) redd[wid] = d2;
  __syncthreads();
  if (tid == 0) redd[0] = redd[0] + redd[1] + redd[2] + redd[3];
  __syncthreads();
  const double var = redd[0] * (1.0 / 1024.0);
  const float rs = (float)(1.0 / sqrt(var + (double)LN_EPS));
  const float muf = (float)mu;

  float4 g = *reinterpret_cast<const float4*>(gamma + tid * 4);
  float4 bb = *reinterpret_cast<const float4*>(beta + tid * 4);
  float4 o;
  o.x = fmaf((x[0] - muf) * rs, g.x, bb.x);
  o.y = fmaf((x[1] - muf) * rs, g.y, bb.y);
  o.z = fmaf((x[2] - muf) * rs, g.z, bb.z);
  o.w = fmaf((x[3] - muf) * rs, g.w, bb.w);
  *reinterpret_cast<float4*>(out + row * 1024 + tid * 4) = o;
}

// ---------------------------------------------------------------------------
// Head: fc_hash (f64 accumulate; sign decides the straight-through bit),
// sigmoid, binarize, fc_cls = code @ W_cls + b_cls.
// ---------------------------------------------------------------------------
__global__ __launch_bounds__(128) void head_kernel(const float* __restrict__ normed,
                                                   const float* __restrict__ W_hash,
                                                   const float* __restrict__ b_hash,
                                                   const float* __restrict__ W_cls,
                                                   const float* __restrict__ b_cls,
                                                   float* __restrict__ out_code,
                                                   float* __restrict__ out_prob,
                                                   float* __restrict__ out_cls) {
  __shared__ float ns[1024];
  __shared__ float cs[64];
  const size_t b = blockIdx.x;
  const int tid = threadIdx.x;

#pragma unroll
  for (int i = 0; i < 2; ++i) {
    const int idx = (tid + i * 128) * 4;
    *reinterpret_cast<float4*>(&ns[idx]) =
        *reinterpret_cast<const float4*>(normed + b * 1024 + idx);
  }
  __syncthreads();

  if (tid < 64) {
    double acc = 0.0;
#pragma unroll 4
    for (int m = 0; m < 1024; ++m)
      acc = fma((double)ns[m], (double)W_hash[m * 64 + tid], acc);
    const float fc = (float)(acc + (double)b_hash[tid]);
    const float pr = 1.f / (1.f + expf(-fc));
    const float code = fc > 0.f ? 1.f : 0.f;
    out_code[b * 64 + tid] = code;
    out_prob[b * 64 + tid] = pr;
    cs[tid] = code;
  }
  __syncthreads();

  if (tid < 100) {
    float acc = b_cls[tid];
#pragma unroll 8
    for (int c = 0; c < 64; ++c)
      if (cs[c] != 0.f) acc += W_cls[c * 100 + tid];
    out_cls[b * 100 + tid] = acc;
  }
}

// ---------------------------------------------------------------------------
extern "C" void kernel_launch(void* const* d_in, const int* in_sizes, int n_in,
                              void* d_out, int out_size, void* d_ws, size_t ws_size,
                              hipStream_t stream) {
  const float* feat = (const float*)d_in[0];    // [8192,2048]
  const float* emb = (const float*)d_in[1];     // [4096,2048]
  const float* W_k = (const float*)d_in[2];     // [2048,1024]
  const float* W_v = (const float*)d_in[3];
  const float* W_q = (const float*)d_in[4];
  const float* W_hash = (const float*)d_in[5];
  const float* b_hash = (const float*)d_in[6];
  const float* ln_g = (const float*)d_in[7];
  const float* ln_b = (const float*)d_in[8];
  const float* W_cls = (const float*)d_in[9];
  const float* b_cls = (const float*)d_in[10];
  float* out = (float*)d_out;

  const int B = 8192, N = 4096, D = 2048, M = 1024;
  const size_t NM = (size_t)N * M;   // 4194304
  const size_t BM = (size_t)B * M;   // 8388608

  // Workspace (floats): k | v | q | att | [splits as u16] | S + S-splits(chunk)
  float* ws = (float*)d_ws;
  float* kf = ws;
  float* vf = kf + NM;
  float* qf = vf + NM;
  float* att = qf + BM;
  u16* qh = (u16*)(att + BM);
  u16* qm = qh + BM;
  u16* ql = qm + BM;
  u16* kh = ql + BM;
  u16* km = kh + NM;
  u16* kl = km + NM;
  u16* vth = kl + NM;
  u16* vtm = vth + NM;
  u16* vtl = vtm + NM;
  float* Sf = (float*)(vtl + NM);

  // fixed floats: 2NM + 2BM + (3BM + 6NM)/2 ; per chunk-row: 4096 + 3*2048 fl
  const size_t fixedFl = 2 * NM + 2 * BM + (3 * BM + 6 * NM) / 2;
  const size_t avail = ws_size / sizeof(float);
  int chunk = 8192;
  while (chunk > 128 && fixedFl + (size_t)chunk * 10240 > avail) chunk >>= 1;
  u16* Sh = (u16*)(Sf + (size_t)chunk * 4096);
  u16* Sm = Sh + (size_t)chunk * 4096;
  u16* Sl = Sm + (size_t)chunk * 4096;

  // Projections (f32, proven)
  gemm128_kv<<<dim3(M / 128, N / 128, 2), 256, 0, stream>>>(emb, W_k, W_v, kf, vf, N, M, D);
  gemm128<0><<<dim3(M / 128, B / 128), 256, 0, stream>>>(feat, W_q, qf, B, M, D);

  // Split q,k ; transpose-split v
  split3k<<<2048, 256, 0, stream>>>(qf, qh, qm, ql, (int)(BM / 4));
  split3k<<<2048, 256, 0, stream>>>(kf, kh, km, kl, (int)(NM / 4));
  tsplit3<<<dim3(M / 32, N / 32), 256, 0, stream>>>(vf, vth, vtm, vtl, N, M);

  // Attention (split3 MFMA), chunked over rows of B
  for (int c0 = 0; c0 < B; c0 += chunk) {
    mfma_bt<<<dim3(N / 128, chunk / 128), 256, 0, stream>>>(
        qh + (size_t)c0 * M, qm + (size_t)c0 * M, ql + (size_t)c0 * M,
        kh, km, kl, Sf, chunk, N, M);
    softmax_split<<<chunk, 256, 0, stream>>>(Sf, Sh, Sm, Sl);
    mfma_bt<<<dim3(M / 128, chunk / 128), 256, 0, stream>>>(
        Sh, Sm, Sl, vth, vtm, vtl, att + (size_t)c0 * M, chunk, M, N);
  }

  // Residual + LayerNorm, then head
  ln_resid<<<B, 256, 0, stream>>>(att, qf, ln_g, ln_b, att);
  head_kernel<<<B, 128, 0, stream>>>(att, W_hash, b_hash, W_cls, b_cls, out,
                                     out + (size_t)B * 64, out + (size_t)B * 128);
}